// Round 4
// baseline (537.482 us; speedup 1.0000x reference)
//
#include <hip/hip_runtime.h>
#include <hip/hip_bf16.h>

typedef __hip_bfloat16 bf16;
typedef short bf16x8 __attribute__((ext_vector_type(8)));
typedef short short4v __attribute__((ext_vector_type(4)));
typedef float f32x4 __attribute__((ext_vector_type(4)));

struct __attribute__((packed, aligned(4))) uf4 { f32x4 v; };
struct __attribute__((packed, aligned(4))) uu4 { uint4 v; };

constexpr int C  = 192;
constexpr int HF = 128;
constexpr int L  = 4096;          // 64*64

__device__ inline float u2f(unsigned u){
    union { unsigned u; float f; } x; x.u = u; return x.f;
}
__device__ inline short f2bf_s(float f){
    bf16 h = __float2bfloat16(f);
    return *reinterpret_cast<short*>(&h);
}

// ---------------- prep: downsample, bf16 split, parity images, ss ----------------
__global__ void prep_kernel(const float* __restrict__ f, const float* __restrict__ b,
                            bf16* __restrict__ fdh, bf16* __restrict__ fdl,
                            bf16* __restrict__ bdh, bf16* __restrict__ bdl,
                            bf16* __restrict__ bpar, float* __restrict__ ss, int batch){
    int pos = blockIdx.x;            // p*64+q
    int p = pos >> 6, q = pos & 63;
    int c = threadIdx.x;             // 0..191
    const float* fb = f + (size_t)batch * HF * HF * C;
    const float* bb = b + (size_t)batch * HF * HF * C;

    float fv = fb[((2*p)*HF + 2*q)*C + c];
    bf16 fh = __float2bfloat16(fv);
    fdh[(size_t)pos*C + c] = fh;
    fdl[(size_t)pos*C + c] = __float2bfloat16(fv - __bfloat162float(fh));

    float b00 = 0.f;
    #pragma unroll
    for (int dx = 0; dx < 2; dx++)
      #pragma unroll
      for (int dy = 0; dy < 2; dy++){
        float bv = bb[((2*p+dx)*HF + (2*q+dy))*C + c];
        int par = dx*2 + dy;
        bpar[((size_t)par*L + pos)*C + c] = __float2bfloat16(bv);   // [par][k=p*64+q][c]
        if (par == 0){
            b00 = bv;
            bf16 bh = __float2bfloat16(bv);
            bdh[(size_t)pos*C + c] = bh;
            bdl[(size_t)pos*C + c] = __float2bfloat16(bv - __bfloat162float(bh));
        }
      }

    __shared__ float red[3];
    float v = b00 * b00;
    #pragma unroll
    for (int o = 32; o > 0; o >>= 1) v += __shfl_down(v, o);
    if ((threadIdx.x & 63) == 0) red[threadIdx.x >> 6] = v;
    __syncthreads();
    if (threadIdx.x == 0) ss[pos] = red[0] + red[1] + red[2];
}

// ---------------- norm (3x3 window of ss) and mask mm ----------------------------
__global__ void normmm_kernel(const float* __restrict__ mask, const float* __restrict__ ss,
                              float* __restrict__ rnorm, float* __restrict__ mmv){
    int pos = blockIdx.x*256 + threadIdx.x;
    int p = pos >> 6, q = pos & 63;
    float s = 0.f, ms = 0.f;
    #pragma unroll
    for (int di = -1; di <= 1; di++)
      #pragma unroll
      for (int dj = -1; dj <= 1; dj++){
        int pp = p + di, qq = q + dj;
        if ((unsigned)pp < 64u && (unsigned)qq < 64u){
            s  += ss[pp*64 + qq];
            ms += mask[(2*pp)*HF + 2*qq];
        }
      }
    float n = fmaxf(sqrtf(s), 1e-4f);
    rnorm[pos] = 1.f / n;
    mmv[pos] = (ms == 0.f) ? 1.f : 0.f;
}

// ---------------- repack bpar[par][k][c] -> bparT[par][c][k] ---------------------
__global__ void repack_kernel(const bf16* __restrict__ bpar, bf16* __restrict__ bparT){
    __shared__ bf16 lds[64][66];
    int c0 = blockIdx.x * 64;
    int k0 = blockIdx.y * 64;
    int par = blockIdx.z;
    const bf16* src = bpar + (size_t)par*L*C;
    bf16* dst = bparT + (size_t)par*C*L;
    int t = threadIdx.x;
    #pragma unroll
    for (int it = 0; it < 16; it++){
        int e = t + it*256; int cc = e & 63, kk = e >> 6;
        lds[kk][cc] = src[(size_t)(k0+kk)*C + c0 + cc];
    }
    __syncthreads();
    #pragma unroll
    for (int it = 0; it < 16; it++){
        int e = t + it*256; int kk = e & 63, cc = e >> 6;
        dst[(size_t)(c0+cc)*L + k0 + kk] = lds[kk][cc];
    }
}

// ---------------- Gram GEMM: G[a,b] = sum_c fd[a,c]*bd[b,c], split-bf16 ----------
__global__ __launch_bounds__(256) void gemm_g(
        const bf16* __restrict__ fdh, const bf16* __restrict__ fdl,
        const bf16* __restrict__ bdh, const bf16* __restrict__ bdl,
        float* __restrict__ G){
    __shared__ __align__(16) bf16 Ah[128][40], Al[128][40], Bh[128][40], Bl[128][40];
    int t = threadIdx.x;
    int m0 = blockIdx.y * 128, n0 = blockIdx.x * 128;
    int wv = t >> 6, lane = t & 63, lr = lane & 15, lq = lane >> 4;
    int wm = (wv >> 1) * 64, wn = (wv & 1) * 64;
    f32x4 acc[4][4] = {};

    for (int kk = 0; kk < 6; kk++){
        int k0 = kk * 32;
        __syncthreads();
        #pragma unroll
        for (int r = 0; r < 2; r++){
            int e = r*256 + t; int row = e >> 2, kc = e & 3;
            *(uint4*)&Ah[row][kc*8] = *(const uint4*)(fdh + (size_t)(m0+row)*C + k0 + kc*8);
            *(uint4*)&Al[row][kc*8] = *(const uint4*)(fdl + (size_t)(m0+row)*C + k0 + kc*8);
            *(uint4*)&Bh[row][kc*8] = *(const uint4*)(bdh + (size_t)(n0+row)*C + k0 + kc*8);
            *(uint4*)&Bl[row][kc*8] = *(const uint4*)(bdl + (size_t)(n0+row)*C + k0 + kc*8);
        }
        __syncthreads();
        bf16x8 ah[4], al[4], bh[4], bl[4];
        #pragma unroll
        for (int mt = 0; mt < 4; mt++){
            ah[mt] = *(bf16x8*)&Ah[wm + mt*16 + lr][lq*8];
            al[mt] = *(bf16x8*)&Al[wm + mt*16 + lr][lq*8];
        }
        #pragma unroll
        for (int nt = 0; nt < 4; nt++){
            bh[nt] = *(bf16x8*)&Bh[wn + nt*16 + lr][lq*8];
            bl[nt] = *(bf16x8*)&Bl[wn + nt*16 + lr][lq*8];
        }
        #pragma unroll
        for (int mt = 0; mt < 4; mt++)
          #pragma unroll
          for (int nt = 0; nt < 4; nt++){
            acc[mt][nt] = __builtin_amdgcn_mfma_f32_16x16x32_bf16(ah[mt], bh[nt], acc[mt][nt], 0,0,0);
            acc[mt][nt] = __builtin_amdgcn_mfma_f32_16x16x32_bf16(ah[mt], bl[nt], acc[mt][nt], 0,0,0);
            acc[mt][nt] = __builtin_amdgcn_mfma_f32_16x16x32_bf16(al[mt], bh[nt], acc[mt][nt], 0,0,0);
          }
    }
    #pragma unroll
    for (int mt = 0; mt < 4; mt++)
      #pragma unroll
      for (int nt = 0; nt < 4; nt++)
        #pragma unroll
        for (int r = 0; r < 4; r++){
            int gr = m0 + wm + mt*16 + lq*4 + r;
            int gc = n0 + wn + nt*16 + lr;
            G[(size_t)gr*L + gc] = acc[mt][nt][r];
        }
}

// ---------------- fused s1 (9-tap) + fuse1 (3-tap diag), 8 outputs/thread --------
__global__ __launch_bounds__(256) void s1f_kernel(const float* __restrict__ G,
                                                  const float* __restrict__ rnorm,
                                                  float* __restrict__ F1){
    int A = blockIdx.y;
    int tB0 = (blockIdx.x*256 + (int)threadIdx.x) * 8;
    const float* gA = G + (size_t)A*L + tB0;

    bool fvA[3]; bool rowOK[3][3]; bool colOK[3][3];
    #pragma unroll
    for (int dd = 0; dd < 3; dd++){
        int A1 = A + dd - 1;
        fvA[dd] = (unsigned)A1 < (unsigned)L;
        int i1 = A1 >> 6, j1 = A1 & 63;
        #pragma unroll
        for (int k = 0; k < 3; k++){
            rowOK[dd][k] = (unsigned)(i1 + k - 1) < 64u;
            colOK[dd][k] = (unsigned)(j1 + k - 1) < 64u;
        }
    }

    float S[3][8];
    #pragma unroll
    for (int dd = 0; dd < 3; dd++)
      #pragma unroll
      for (int e = 0; e < 8; e++) S[dd][e] = 0.f;

    #pragma unroll
    for (int di = 0; di < 3; di++){
        float g[5][8];
        #pragma unroll
        for (int s = 0; s < 5; s++){
            const float* p = gA + (long)((di-1)*64 + (s-2)) * (long)(L+1);
            *(f32x4*)&g[s][0] = ((const uf4*)p)->v;
            *(f32x4*)&g[s][4] = ((const uf4*)(p+4))->v;
        }
        #pragma unroll
        for (int dd = 0; dd < 3; dd++){
            const int d = dd - 1;
            #pragma unroll
            for (int e = 0; e < 8; e++){
                int B1 = tB0 + e + d;
                int p1 = B1 >> 6, q1 = B1 & 63;
                bool rm = rowOK[dd][di] && ((unsigned)(p1 + di - 1) < 64u);
                float r = 0.f;
                #pragma unroll
                for (int dj = 0; dj < 3; dj++){
                    bool cm = colOK[dd][dj] && ((unsigned)(q1 + dj - 1) < 64u);
                    r += cm ? g[d + dj + 1][e] : 0.f;
                }
                S[dd][e] += rm ? r : 0.f;
            }
        }
    }

    float rn[12];
    const float* rp = rnorm + tB0 - 2;
    *(f32x4*)&rn[0] = ((const uf4*)rp)->v;
    *(f32x4*)&rn[4] = ((const uf4*)(rp+4))->v;
    *(f32x4*)&rn[8] = ((const uf4*)(rp+8))->v;

    float acc[8];
    #pragma unroll
    for (int e = 0; e < 8; e++){
        float a = 0.f;
        #pragma unroll
        for (int dd = 0; dd < 3; dd++){
            const int d = dd - 1;
            int B1 = tB0 + e + d;
            bool ok = fvA[dd] && ((unsigned)B1 < (unsigned)L);
            float wd = ok ? rn[e + d + 2] : 0.f;
            a += wd * S[dd][e];
        }
        acc[e] = a;
    }
    float* o = F1 + (size_t)A*L + tB0;
    *(f32x4*)(o)     = *(f32x4*)&acc[0];
    *(f32x4*)(o + 4) = *(f32x4*)&acc[4];
}

// -------- fuse2 (3-tap, transposed-flat wrap) + mask + softmax, vectorized -------
__global__ __launch_bounds__(256) void fsoft_kernel(const float* __restrict__ F1,
                                                    const float* __restrict__ mmv,
                                                    bf16* __restrict__ attn){
    int A = blockIdx.x, t = threadIdx.x;
    int i = A >> 6, j = A & 63;
    bool pok = A < L-1, mok = A > 0;
    int rowp = (i < 63) ? A + 64 : j + 1;
    int rowm = (i > 0)  ? A - 64 : 63*64 + j - 1;
    const float* FA = F1 + (size_t)A*L;
    const float* FP = F1 + (size_t)rowp*L;
    const float* FM = F1 + (size_t)rowm*L;

    float z[16]; float mx = -1e30f;
    #pragma unroll
    for (int it = 0; it < 4; it++){
        int b0 = (it*256 + t)*4;
        int p = b0 >> 6, q0 = b0 & 63;
        f32x4 v  = *(const f32x4*)(FA + b0);
        f32x4 mv = *(const f32x4*)(mmv + b0);
        f32x4 tp, tm;
        if (p < 63) tp = ((const uf4*)(FP + b0 + 64))->v;
        else        tp = ((const uf4*)(FP + q0 + 1))->v;
        if (p > 0)  tm = ((const uf4*)(FM + b0 - 64))->v;
        else        tm = ((const uf4*)(FM + 63*64 + q0 - 1))->v;
        #pragma unroll
        for (int e = 0; e < 4; e++){
            int Bq = b0 + e;
            float val = v[e];
            if (pok && Bq < L-1) val += tp[e];
            if (mok && Bq > 0)   val += tm[e];
            val = val * mv[e] * 10.f;
            z[it*4+e] = val; mx = fmaxf(mx, val);
        }
    }
    __shared__ float red[4];
    #pragma unroll
    for (int o = 32; o > 0; o >>= 1) mx = fmaxf(mx, __shfl_down(mx, o));
    if ((t & 63) == 0) red[t >> 6] = mx;
    __syncthreads();
    mx = fmaxf(fmaxf(red[0], red[1]), fmaxf(red[2], red[3]));
    float sm = 0.f;
    #pragma unroll
    for (int it = 0; it < 16; it++){ z[it] = __expf(z[it] - mx); sm += z[it]; }
    #pragma unroll
    for (int o = 32; o > 0; o >>= 1) sm += __shfl_down(sm, o);
    __syncthreads();
    if ((t & 63) == 0) red[t >> 6] = sm;
    __syncthreads();
    sm = red[0] + red[1] + red[2] + red[3];
    float inv = 1.f / sm;
    bf16* aA = attn + (size_t)A*L;
    #pragma unroll
    for (int it = 0; it < 4; it++){
        int b0 = (it*256 + t)*4;
        f32x4 mv = *(const f32x4*)(mmv + b0);
        short sv[4];
        #pragma unroll
        for (int e = 0; e < 4; e++)
            sv[e] = f2bf_s(z[it*4+e] * inv * mv[e]);
        *(short4v*)(aA + b0) = *(short4v*)&sv[0];
    }
}

// ---------------- fused v4 + paste GEMM, software-pipelined ----------------------
struct PR {
    uint w1[4], w2[4], w3[5], w4[5];
    uint4 b[6];
};

__global__ __launch_bounds__(256, 2) void gemm_paste(
        const bf16* __restrict__ attn, const bf16* __restrict__ bparT,
        float* __restrict__ out, int batch){
    __shared__ __align__(16) bf16 Ab[2][32][72];
    __shared__ __align__(16) bf16 Bb[2][192][72];
    int t = threadIdx.x;
    int par = blockIdx.y;
    int m0 = blockIdx.x * 32;
    int dx = par >> 1, dy = par & 1;
    int sx = 1 - 2*dx, sy = 1 - 2*dy;
    int wv = t >> 6, lane = t & 63, lr = lane & 15, lq = lane >> 4;

    int arow = t >> 3, acol = (t & 7) * 8;
    int m = m0 + arow; int X = m >> 6, Yv = m & 63;
    bool r2 = (unsigned)(X - sx) < 64u;
    bool r3 = (unsigned)(Yv - sy) < 64u;
    bool r4 = r2 && r3;
    const bf16* row1 = attn + (size_t)m*L + acol;
    const bf16* row2 = row1 - (long)(64*sx) * (long)(L+1);
    const bf16* row3 = row1 - (long)sy * (long)(L+1);
    const bf16* row4 = row1 - (long)(64*sx + sy) * (long)(L+1);
    const bf16* bbase = bparT + (size_t)par*C*L + (size_t)arow*L + acol;
    bool qok[8];
    #pragma unroll
    for (int e = 0; e < 8; e++) qok[e] = (unsigned)(acol + e - sy) < 64u;

    f32x4 acc[2][3] = {};
    PR r0, r1;

    auto load = [&](PR& r, int kk){
        int be = kk*64;
        *(uint4*)&r.w1[0] = ((const uu4*)(row1 + be))->v;
        *(uint4*)&r.w2[0] = ((const uu4*)(row2 + be))->v;
        const uint* p3 = (const uint*)(row3 + be - 1);
        *(uint4*)&r.w3[0] = ((const uu4*)p3)->v;  r.w3[4] = p3[4];
        const uint* p4 = (const uint*)(row4 + be - 1);
        *(uint4*)&r.w4[0] = ((const uu4*)p4)->v;  r.w4[4] = p4[4];
        #pragma unroll
        for (int rr = 0; rr < 6; rr++)
            r.b[rr] = *(const uint4*)(bbase + (size_t)rr*32*L + be);
    };

    auto proc = [&](PR& r, int kk, int buf){
        bool c2u = (unsigned)(kk - sx) < 64u;
        bool m2 = r2 && c2u, m3 = r3, m4 = r4 && c2u;
        short sv[8];
        #pragma unroll
        for (int ii = 0; ii < 4; ii++){
            uint a1 = r.w1[ii];
            uint a2 = r.w2[ii];
            uint a3 = (r.w3[ii] >> 16) | (r.w3[ii+1] << 16);
            uint a4 = (r.w4[ii] >> 16) | (r.w4[ii+1] << 16);
            float f1l = u2f(a1 << 16), f1h = u2f(a1 & 0xffff0000u);
            float f2l = u2f(a2 << 16), f2h = u2f(a2 & 0xffff0000u);
            float f3l = u2f(a3 << 16), f3h = u2f(a3 & 0xffff0000u);
            float f4l = u2f(a4 << 16), f4h = u2f(a4 & 0xffff0000u);
            float sl = f1l + (m2 ? f2l : 0.f)
                     + ((m3 && qok[2*ii  ]) ? f3l : 0.f)
                     + ((m4 && qok[2*ii  ]) ? f4l : 0.f);
            float sh = f1h + (m2 ? f2h : 0.f)
                     + ((m3 && qok[2*ii+1]) ? f3h : 0.f)
                     + ((m4 && qok[2*ii+1]) ? f4h : 0.f);
            sv[2*ii]   = f2bf_s(sl);
            sv[2*ii+1] = f2bf_s(sh);
        }
        *(bf16x8*)&Ab[buf][arow][acol] = *(bf16x8*)&sv[0];
        #pragma unroll
        for (int rr = 0; rr < 6; rr++)
            *(uint4*)&Bb[buf][rr*32 + arow][acol] = r.b[rr];
        __syncthreads();
        #pragma unroll
        for (int kk2 = 0; kk2 < 2; kk2++){
            bf16x8 a[2], bfr[3];
            #pragma unroll
            for (int mt = 0; mt < 2; mt++)
                a[mt] = *(bf16x8*)&Ab[buf][mt*16 + lr][kk2*32 + lq*8];
            #pragma unroll
            for (int nt = 0; nt < 3; nt++)
                bfr[nt] = *(bf16x8*)&Bb[buf][wv*48 + nt*16 + lr][kk2*32 + lq*8];
            #pragma unroll
            for (int mt = 0; mt < 2; mt++)
              #pragma unroll
              for (int nt = 0; nt < 3; nt++)
                acc[mt][nt] = __builtin_amdgcn_mfma_f32_16x16x32_bf16(a[mt], bfr[nt], acc[mt][nt], 0,0,0);
        }
    };

    load(r0, 0);
    for (int kk = 0; kk < 64; kk += 2){
        load(r1, kk + 1);
        proc(r0, kk, 0);
        if (kk + 2 < 64) load(r0, kk + 2);
        proc(r1, kk + 1, 1);
    }

    #pragma unroll
    for (int mt = 0; mt < 2; mt++)
      #pragma unroll
      for (int nt = 0; nt < 3; nt++)
        #pragma unroll
        for (int r = 0; r < 4; r++){
            int mm = m0 + mt*16 + lq*4 + r;
            int Xo = mm >> 6, Yo = mm & 63;
            int x = 2*Xo + dx, y = 2*Yo + dy, c2 = wv*48 + nt*16 + lr;
            out[(size_t)((batch*HF + x)*HF + y)*C + c2] = 0.25f * acc[mt][nt][r];
        }
}

// ---------------- host ----------------
extern "C" void kernel_launch(void* const* d_in, const int* in_sizes, int n_in,
                              void* d_out, int out_size, void* d_ws, size_t ws_size,
                              hipStream_t stream){
    const float* f    = (const float*)d_in[0];
    const float* b    = (const float*)d_in[1];
    const float* mask = (const float*)d_in[2];
    float* out = (float*)d_out;
    char* ws = (char*)d_ws;

    constexpr size_t off_G     = 1179648ull;               // 64 MB, 1.125 MB guards
    constexpr size_t off_F1    = 69468160ull;              // 64 MB
    constexpr size_t off_attn  = 137232384ull;             // 32 MB, 640 KB guards
    constexpr size_t off_bparT = 171442176ull;             // 6.29 MB
    constexpr size_t off_ss    = 177733632ull;
    constexpr size_t off_rn    = 177750016ull;
    constexpr size_t off_mmv   = 177766656ull;

    float* G    = (float*)(ws + off_G);
    float* F1   = (float*)(ws + off_F1);
    bf16*  attn = (bf16*) (ws + off_attn);
    bf16*  bpar = (bf16*) (ws + off_F1);                   // alias: dead before F1 written
    bf16*  fdh  = (bf16*) (ws + off_attn);                 // alias: dead before attn written
    bf16*  fdl  = (bf16*) (ws + off_attn + 1572864ull);
    bf16*  bdh  = (bf16*) (ws + off_attn + 3145728ull);
    bf16*  bdl  = (bf16*) (ws + off_attn + 4718592ull);
    bf16*  bparT= (bf16*) (ws + off_bparT);
    float* ss    = (float*)(ws + off_ss);
    float* rnorm = (float*)(ws + off_rn) + 16;
    float* mmv   = (float*)(ws + off_mmv);

    for (int batch = 0; batch < 2; batch++){
        prep_kernel  <<<dim3(4096),    dim3(192), 0, stream>>>(f, b, fdh, fdl, bdh, bdl, bpar, ss, batch);
        normmm_kernel<<<dim3(16),      dim3(256), 0, stream>>>(mask, ss, rnorm, mmv);
        repack_kernel<<<dim3(3,64,4),  dim3(256), 0, stream>>>(bpar, bparT);
        gemm_g       <<<dim3(32,32),   dim3(256), 0, stream>>>(fdh, fdl, bdh, bdl, G);
        s1f_kernel   <<<dim3(2,4096),  dim3(256), 0, stream>>>(G, rnorm, F1);
        fsoft_kernel <<<dim3(4096),    dim3(256), 0, stream>>>(F1, mmv, attn);
        gemm_paste   <<<dim3(128,4),   dim3(256), 0, stream>>>(attn, bparT, out, batch);
    }
}